// Round 1
// 241.522 us; speedup vs baseline: 1.1102x; 1.1102x over previous
//
#include <hip/hip_runtime.h>
#include <hip/hip_bf16.h>

#define N_NODES 50000
#define D_IN 128
#define D_OUT 64
#define N_ETYPES 3
#define E_PER_ETYPE 500000
#define N_EDGES (N_ETYPES * E_PER_ETYPE)
#define CAP1 16   // primary bucket: 32B (ushort) per cell
#define CAP2 30   // spill (deg>16: ~2.6% of cells; P(deg>46)~1e-18) -- shrunk from 32 (R8) to fund Wt
#define NB_FEAT ((N_NODES * D_IN / 4) / 256)   // 6250
#define NB_W ((D_IN * D_OUT) / 256)            // 32

typedef __attribute__((ext_vector_type(8))) short short8;
typedef __attribute__((ext_vector_type(4))) float f32x4;

static __device__ __forceinline__ unsigned short f2bf(float f) {
    unsigned int x = __float_as_uint(f);
    unsigned int lsb = (x >> 16) & 1u;
    x += 0x7fffu + lsb;          // round-to-nearest-even
    return (unsigned short)(x >> 16);
}

// Branch-free tanh: ~6 VALU vs ~35 for libm tanhf. |err| ~ 1e-6, budget 0.038.
static __device__ __forceinline__ float fast_tanh(float x) {
    float e = __expf(2.0f * x);
    return 1.0f - 2.0f * __builtin_amdgcn_rcpf(e + 1.0f);
}

static __device__ __forceinline__ short8 as_s8(uint4 u) {
    union { uint4 u; short8 s; } cv; cv.u = u; return cv.s;
}

static __device__ __forceinline__ void accum8(float* ax, uint4 p) {
    ax[0] += __uint_as_float(p.x << 16);
    ax[1] += __uint_as_float(p.x & 0xffff0000u);
    ax[2] += __uint_as_float(p.y << 16);
    ax[3] += __uint_as_float(p.y & 0xffff0000u);
    ax[4] += __uint_as_float(p.z << 16);
    ax[5] += __uint_as_float(p.z & 0xffff0000u);
    ax[6] += __uint_as_float(p.w << 16);
    ax[7] += __uint_as_float(p.w & 0xffff0000u);
}

// feat (fp32) -> featbf (bf16), 4 elems/thread. R8: extra NB_W blocks build
// Wt[n][k] = bf16(W[k][n]) -- the B^T operand layout for mfma_f32_16x16x32_bf16.
__global__ __launch_bounds__(256) void convert_kernel(
    const float* __restrict__ feat,
    unsigned short* __restrict__ featbf,
    const float* __restrict__ W,
    unsigned short* __restrict__ wtbf)
{
    int b = blockIdx.x;
    if (b < NB_FEAT) {
        int i = b * 256 + threadIdx.x;
        const float4* f4 = (const float4*)feat;
        float4 v = f4[i];
        ushort4 o;
        o.x = f2bf(v.x); o.y = f2bf(v.y); o.z = f2bf(v.z); o.w = f2bf(v.w);
        ((ushort4*)featbf)[i] = o;
    } else {
        int i = (b - NB_FEAT) * 256 + threadIdx.x;   // 0..8191
        int n = i >> 7;        // output col 0..63
        int k = i & 127;       // input dim 0..127
        wtbf[i] = f2bf(W[k * D_OUT + n]);   // 32KB one-shot; uncoalesced reads are fine
    }
}

// Flat one-pass binning (R3 structure, ushort payload). UNCHANGED logic.
__global__ __launch_bounds__(256) void fill_kernel(
    const int* __restrict__ edge_index,
    unsigned short* __restrict__ bucket1,
    unsigned short* __restrict__ spill,
    int* __restrict__ cnt)
{
    int gid = blockIdx.x * 256 + threadIdx.x;
    if (gid >= N_EDGES) return;
    int t  = gid / E_PER_ETYPE;
    int ei = gid - t * E_PER_ETYPE;
    const int* base = edge_index + (long long)t * 2 * E_PER_ETYPE;
    int src = base[ei];                 // coalesced
    int dst = base[E_PER_ETYPE + ei];   // coalesced
    int cell = t * N_NODES + dst;
    int pos = atomicAdd(cnt + cell, 1);
    if (pos < CAP1)
        bucket1[(long long)cell * CAP1 + pos] = (unsigned short)src;
    else if (pos < CAP1 + CAP2)
        spill[(long long)cell * CAP2 + (pos - CAP1)] = (unsigned short)src;
}

// Fused gather + epilogue + MFMA linear. 512 thr = 8 waves = 8 nodes/block.
// R8 changes vs R7:
//  - neighbor loop unrolled x2 (8 rows/iter, two uint4 gathers in flight;
//    tail rows clamped to d-1 so dead loads hit a hot line, not random HBM)
//  - h stored as bf16 into a 16x128 LDS tile (rows 8..15 zero), XOR-swizzled
//    byte ^= row<<4 so the MFMA A-frag ds_read_b128 (256B row stride) is
//    conflict-free (G4 pattern)
//  - final [8x128]@[128x64] linear on matrix cores: waves 0..3 each own one
//    16x16 output tile, 4x mfma_f32_16x16x32_bf16 over K=128; B-frags
//    prefetched from Wt (B^T layout) before the barrier; bias via C-init.
//    Removes 128 FMA + 256 ds_read_b32 per node (1.6 GB LDS traffic) and the
//    32KB Ws staging (LDS 37KB -> 4KB).
__global__ __launch_bounds__(512) void gather_linear_kernel(
    const float* __restrict__ feat,
    const unsigned short* __restrict__ featbf,
    const unsigned short* __restrict__ wtbf,
    const float* __restrict__ bg,
    const unsigned short* __restrict__ bucket1,
    const unsigned short* __restrict__ spill,
    const int* __restrict__ cnt,
    float* __restrict__ out)
{
    __shared__ unsigned short hsb[16 * 128];   // 4KB bf16 h-tile, rows 8..15 = 0

    int tid = threadIdx.x;
    ((unsigned int*)hsb)[512 + tid] = 0;       // zero pad rows 8..15 (512 uints)

    int wave = tid >> 6;
    int lane = tid & 63;
    int sub  = lane >> 4;     // subgroup 0..3
    int sl   = lane & 15;     // owns dims [8sl..8sl+7] for gather
    int n = blockIdx.x * 8 + wave;       // 6250*8 == 50000 exactly

    // Preload deg + up to 46 neighbor indices per etype (lanes 0..45).
    int deg[N_ETYPES], idx[N_ETYPES];
    #pragma unroll
    for (int t = 0; t < N_ETYPES; t++) {
        int cell = t * N_NODES + n;
        int dg = cnt[cell];                       // wave-uniform
        int id = 0;
        if (lane < CAP1) id = bucket1[(long long)cell * CAP1 + lane];
        else if (lane < CAP1 + CAP2 && dg > CAP1)
            id = spill[(long long)cell * CAP2 + (lane - CAP1)];
        deg[t] = dg; idx[t] = id;
    }

    const uint4* fb4 = (const uint4*)featbf;   // row = 16 uint4 (256B)
    int k0 = 2 * sub;
    float s0 = 0.0f, s1 = 0.0f;

    #pragma unroll
    for (int t = 0; t < N_ETYPES; t++) {
        int d = (deg[t] < CAP1 + CAP2) ? deg[t] : (CAP1 + CAP2);
        float ax[8];
        #pragma unroll
        for (int k = 0; k < 8; k++) ax[k] = 0.0f;
        for (int j = 0; j < d; j += 8) {
            int ra = j + sub;
            int rb = j + 4 + sub;
            int ca = (ra < d - 1) ? ra : (d - 1);     // clamp dead rows to a hot line
            int cb = (rb < d - 1) ? rb : (d - 1);
            int sa = __shfl(idx[t], ca);
            int sb = __shfl(idx[t], cb);
            uint4 pa = fb4[(long long)sa * 16 + sl];  // two independent 256B
            uint4 pb = fb4[(long long)sb * 16 + sl];  // gathers in flight
            if (ra < d) accum8(ax, pa);
            if (rb < d) accum8(ax, pb);
        }
        // Cross-subgroup reduce: lanes l, l^16, l^32, l^48 hold partials of
        // the same 8 dims. After this every lane has the full sums.
        #pragma unroll
        for (int k = 0; k < 8; k++) {
            ax[k] += __shfl_xor(ax[k], 16);
            ax[k] += __shfl_xor(ax[k], 32);
        }
        float inv = 1.0f / (float)((deg[t] > 0) ? deg[t] : 1);
        s0 += fast_tanh(ax[k0] * inv);      // dims D0=8sl+2sub, D0+1 only
        s1 += fast_tanh(ax[k0 + 1] * inv);
    }

    // Epilogue h-compute: lane owns dims D0=8sl+2sub, D0+1 -> fp32 residual,
    // tanh, pack to bf16 pair, swizzled LDS store (2-way banks: free).
    float2 f = ((const float2*)feat)[(long long)n * 64 + (4 * sl + sub)];
    float hx = fast_tanh(f.x + 0.5f * s0);
    float hy = fast_tanh(f.y + 0.5f * s1);
    unsigned int hp = (unsigned int)f2bf(hx) | ((unsigned int)f2bf(hy) << 16);
    int wb = wave * 256 + ((16 * sl + 4 * sub) ^ (wave << 4));
    ((unsigned int*)hsb)[wb >> 2] = hp;

    // Waves 0..3: prefetch B-frags + bias from global BEFORE the barrier so
    // the ~300cy latency hides under the sync.
    uint4 b0 = {0,0,0,0}, b1 = {0,0,0,0}, b2 = {0,0,0,0}, b3 = {0,0,0,0};
    float bias = 0.0f;
    int sg = lane >> 4;
    if (wave < 4) {
        int nrow = wave * 16 + (lane & 15);          // output col 0..63
        const uint4* wt4 = (const uint4*)wtbf;       // Wt[n][k] bf16, 16 uint4/row
        b0 = wt4[nrow * 16 +  0 + sg];
        b1 = wt4[nrow * 16 +  4 + sg];
        b2 = wt4[nrow * 16 +  8 + sg];
        b3 = wt4[nrow * 16 + 12 + sg];
        bias = bg[nrow];
    }
    __syncthreads();

    if (wave < 4) {
        // A-frag: lane l -> h row (l&15), k = ks*32 + sg*8 .. +7 (16B, swizzled)
        int row = lane & 15;
        int rbase = row * 256;
        int rx = (row & 7) << 4;
        const uint4* h4 = (const uint4*)hsb;
        uint4 a0 = h4[(rbase + (( 0 + sg * 16) ^ rx)) >> 4];
        uint4 a1 = h4[(rbase + (( 64 + sg * 16) ^ rx)) >> 4];
        uint4 a2 = h4[(rbase + ((128 + sg * 16) ^ rx)) >> 4];
        uint4 a3 = h4[(rbase + ((192 + sg * 16) ^ rx)) >> 4];

        f32x4 c = {bias, bias, bias, bias};          // bias via C-init
        c = __builtin_amdgcn_mfma_f32_16x16x32_bf16(as_s8(a0), as_s8(b0), c, 0, 0, 0);
        c = __builtin_amdgcn_mfma_f32_16x16x32_bf16(as_s8(a1), as_s8(b1), c, 0, 0, 0);
        c = __builtin_amdgcn_mfma_f32_16x16x32_bf16(as_s8(a2), as_s8(b2), c, 0, 0, 0);
        c = __builtin_amdgcn_mfma_f32_16x16x32_bf16(as_s8(a3), as_s8(b3), c, 0, 0, 0);

        // C/D layout (m89-verified): col = lane&15, row = sg*4 + i.
        // Rows 8..15 are the zero padding -> not stored.
        #pragma unroll
        for (int i = 0; i < 4; i++) {
            int orow = sg * 4 + i;
            if (orow < 8)
                out[(long long)(blockIdx.x * 8 + orow) * 64 + wave * 16 + (lane & 15)] = c[i];
        }
    }
}

extern "C" void kernel_launch(void* const* d_in, const int* in_sizes, int n_in,
                              void* d_out, int out_size, void* d_ws, size_t ws_size,
                              hipStream_t stream) {
    const float* feat = (const float*)d_in[0];
    const float* W    = (const float*)d_in[1];
    const float* b    = (const float*)d_in[2];
    const int* edge_index = (const int*)d_in[3];
    float* out = (float*)d_out;

    size_t featbf_bytes  = (size_t)N_NODES * D_IN * sizeof(unsigned short);            // 12.8 MB
    size_t bucket1_bytes = (size_t)N_ETYPES * N_NODES * CAP1 * sizeof(unsigned short); //  4.8 MB
    size_t spill_bytes   = (size_t)N_ETYPES * N_NODES * CAP2 * sizeof(unsigned short); //  9.0 MB
    size_t cnt_bytes     = (size_t)N_ETYPES * N_NODES * sizeof(int);                   //  0.6 MB
    size_t wtbf_bytes    = (size_t)D_IN * D_OUT * sizeof(unsigned short);              // 16 KB
    if (ws_size < featbf_bytes + bucket1_bytes + spill_bytes + cnt_bytes + wtbf_bytes)
        return;  // sentinel: out stays 0 (absmax would read 1.898)

    unsigned short* featbf  = (unsigned short*)d_ws;
    unsigned short* bucket1 = (unsigned short*)((char*)d_ws + featbf_bytes);
    unsigned short* spill   = (unsigned short*)((char*)d_ws + featbf_bytes + bucket1_bytes);
    int* cnt = (int*)((char*)d_ws + featbf_bytes + bucket1_bytes + spill_bytes);
    unsigned short* wtbf = (unsigned short*)((char*)d_ws + featbf_bytes + bucket1_bytes
                                             + spill_bytes + cnt_bytes);   // 16B-aligned (27,200,000)

    hipMemsetAsync(cnt, 0, cnt_bytes, stream);

    convert_kernel<<<NB_FEAT + NB_W, 256, 0, stream>>>(feat, featbf, W, wtbf);

    fill_kernel<<<(N_EDGES + 255) / 256, 256, 0, stream>>>(edge_index, bucket1, spill, cnt);

    gather_linear_kernel<<<N_NODES / 8, 512, 0, stream>>>(
        feat, featbf, wtbf, b, bucket1, spill, cnt, out);
}

// Round 2
// 216.934 us; speedup vs baseline: 1.2360x; 1.1133x over previous
//
#include <hip/hip_runtime.h>
#include <hip/hip_bf16.h>

#define N_NODES 50000
#define D_IN 128
#define D_OUT 64
#define N_ETYPES 3
#define E_PER_ETYPE 500000
#define N_EDGES (N_ETYPES * E_PER_ETYPE)
#define CAP1 16   // primary bucket: 32B (ushort) per cell
#define CAP2 30   // spill (deg>16: ~2.6% of cells; P(deg>46)~1e-18)
#define NB_FEAT ((N_NODES * D_IN / 4) / 256)   // 6250
#define NB_W ((D_IN * D_OUT) / 256)            // 32
#define CHUNK_EDGES 2048                        // 256 thr x 8 edges
#define N_CHUNKS ((N_EDGES + CHUNK_EDGES - 1) / CHUNK_EDGES)   // 733

typedef __attribute__((ext_vector_type(8))) short short8;
typedef __attribute__((ext_vector_type(4))) float f32x4;

static __device__ __forceinline__ unsigned short f2bf(float f) {
    unsigned int x = __float_as_uint(f);
    unsigned int lsb = (x >> 16) & 1u;
    x += 0x7fffu + lsb;          // round-to-nearest-even
    return (unsigned short)(x >> 16);
}

// Branch-free tanh: ~6 VALU vs ~35 for libm tanhf. |err| ~ 1e-6, budget 0.038.
static __device__ __forceinline__ float fast_tanh(float x) {
    float e = __expf(2.0f * x);
    return 1.0f - 2.0f * __builtin_amdgcn_rcpf(e + 1.0f);
}

static __device__ __forceinline__ short8 as_s8(uint4 u) {
    union { uint4 u; short8 s; } cv; cv.u = u; return cv.s;
}

static __device__ __forceinline__ void accum8(float* ax, uint4 p) {
    ax[0] += __uint_as_float(p.x << 16);
    ax[1] += __uint_as_float(p.x & 0xffff0000u);
    ax[2] += __uint_as_float(p.y << 16);
    ax[3] += __uint_as_float(p.y & 0xffff0000u);
    ax[4] += __uint_as_float(p.z << 16);
    ax[5] += __uint_as_float(p.z & 0xffff0000u);
    ax[6] += __uint_as_float(p.w << 16);
    ax[7] += __uint_as_float(p.w & 0xffff0000u);
}

// feat (fp32) -> featbf (bf16), 4 elems/thread. Extra NB_W blocks build
// Wt[n][k] = bf16(W[k][n]) -- the B^T operand layout for mfma_f32_16x16x32_bf16.
__global__ __launch_bounds__(256) void convert_kernel(
    const float* __restrict__ feat,
    unsigned short* __restrict__ featbf,
    const float* __restrict__ W,
    unsigned short* __restrict__ wtbf)
{
    int b = blockIdx.x;
    if (b < NB_FEAT) {
        int i = b * 256 + threadIdx.x;
        const float4* f4 = (const float4*)feat;
        float4 v = f4[i];
        ushort4 o;
        o.x = f2bf(v.x); o.y = f2bf(v.y); o.z = f2bf(v.z); o.w = f2bf(v.w);
        ((ushort4*)featbf)[i] = o;
    } else {
        int i = (b - NB_FEAT) * 256 + threadIdx.x;   // 0..8191
        int n = i >> 7;        // output col 0..63
        int k = i & 127;       // input dim 0..127
        wtbf[i] = f2bf(W[k * D_OUT + n]);   // 32KB one-shot; uncoalesced reads are fine
    }
}

// R9: XCD-sliced one-pass binning. dst-space is split into 8 slices of 6250
// nodes; block (chunk, slice=blockIdx&7) reads chunk's edges (coalesced, L3-
// resident on re-reads) and bins ONLY dsts in its slice. Under round-robin
// dispatch slice s lands on XCD s, so each XCD's write working set is one
// 1.8MB bucket slice + 75KB cnt slice -> resident in its private 4MB L2:
// dirty lines written back once (predict WRITE_SIZE 82MB -> ~15-20MB) and all
// same-cell atomic contention stays on one XCD. Correctness is mapping-
// independent: every edge matches exactly one slice. Cost: 8x edge reads
// (96MB) from L3 at multi-TB/s -- cheap vs the write churn it removes.
__global__ __launch_bounds__(256) void fill_kernel(
    const int* __restrict__ edge_index,
    unsigned short* __restrict__ bucket1,
    unsigned short* __restrict__ spill,
    int* __restrict__ cnt)
{
    int slice = blockIdx.x & 7;
    int chunk = blockIdx.x >> 3;
    int e0 = chunk * CHUNK_EDGES + threadIdx.x;
    #pragma unroll
    for (int k = 0; k < CHUNK_EDGES / 256; k++) {
        int e = e0 + k * 256;
        if (e < N_EDGES) {
            int t  = e / E_PER_ETYPE;            // const divisor -> magic mul
            int ei = e - t * E_PER_ETYPE;
            const int* base = edge_index + (long long)t * 2 * E_PER_ETYPE;
            int dst = base[E_PER_ETYPE + ei];    // coalesced
            // s = dst/6250 exactly, for dst in [0,50000): magic 2^32/6250 rounded up
            int s = (int)(((unsigned long long)(unsigned)dst * 687195ull) >> 32);
            if (s == slice) {
                int src = base[ei];
                int cell = t * N_NODES + dst;
                int pos = atomicAdd(cnt + cell, 1);
                if (pos < CAP1)
                    bucket1[(long long)cell * CAP1 + pos] = (unsigned short)src;
                else if (pos < CAP1 + CAP2)
                    spill[(long long)cell * CAP2 + (pos - CAP1)] = (unsigned short)src;
            }
        }
    }
}

// Fused gather + epilogue + MFMA linear. 512 thr = 8 waves = 8 nodes/block.
// UNCHANGED from R8 (so this round's delta is fully attributable to fill).
__global__ __launch_bounds__(512) void gather_linear_kernel(
    const float* __restrict__ feat,
    const unsigned short* __restrict__ featbf,
    const unsigned short* __restrict__ wtbf,
    const float* __restrict__ bg,
    const unsigned short* __restrict__ bucket1,
    const unsigned short* __restrict__ spill,
    const int* __restrict__ cnt,
    float* __restrict__ out)
{
    __shared__ unsigned short hsb[16 * 128];   // 4KB bf16 h-tile, rows 8..15 = 0

    int tid = threadIdx.x;
    ((unsigned int*)hsb)[512 + tid] = 0;       // zero pad rows 8..15 (512 uints)

    int wave = tid >> 6;
    int lane = tid & 63;
    int sub  = lane >> 4;     // subgroup 0..3
    int sl   = lane & 15;     // owns dims [8sl..8sl+7] for gather
    int n = blockIdx.x * 8 + wave;       // 6250*8 == 50000 exactly

    // Preload deg + up to 46 neighbor indices per etype (lanes 0..45).
    int deg[N_ETYPES], idx[N_ETYPES];
    #pragma unroll
    for (int t = 0; t < N_ETYPES; t++) {
        int cell = t * N_NODES + n;
        int dg = cnt[cell];                       // wave-uniform
        int id = 0;
        if (lane < CAP1) id = bucket1[(long long)cell * CAP1 + lane];
        else if (lane < CAP1 + CAP2 && dg > CAP1)
            id = spill[(long long)cell * CAP2 + (lane - CAP1)];
        deg[t] = dg; idx[t] = id;
    }

    const uint4* fb4 = (const uint4*)featbf;   // row = 16 uint4 (256B)
    int k0 = 2 * sub;
    float s0 = 0.0f, s1 = 0.0f;

    #pragma unroll
    for (int t = 0; t < N_ETYPES; t++) {
        int d = (deg[t] < CAP1 + CAP2) ? deg[t] : (CAP1 + CAP2);
        float ax[8];
        #pragma unroll
        for (int k = 0; k < 8; k++) ax[k] = 0.0f;
        for (int j = 0; j < d; j += 8) {
            int ra = j + sub;
            int rb = j + 4 + sub;
            int ca = (ra < d - 1) ? ra : (d - 1);     // clamp dead rows to a hot line
            int cb = (rb < d - 1) ? rb : (d - 1);
            int sa = __shfl(idx[t], ca);
            int sb = __shfl(idx[t], cb);
            uint4 pa = fb4[(long long)sa * 16 + sl];  // two independent 256B
            uint4 pb = fb4[(long long)sb * 16 + sl];  // gathers in flight
            if (ra < d) accum8(ax, pa);
            if (rb < d) accum8(ax, pb);
        }
        // Cross-subgroup reduce: lanes l, l^16, l^32, l^48 hold partials of
        // the same 8 dims. After this every lane has the full sums.
        #pragma unroll
        for (int k = 0; k < 8; k++) {
            ax[k] += __shfl_xor(ax[k], 16);
            ax[k] += __shfl_xor(ax[k], 32);
        }
        float inv = 1.0f / (float)((deg[t] > 0) ? deg[t] : 1);
        s0 += fast_tanh(ax[k0] * inv);      // dims D0=8sl+2sub, D0+1 only
        s1 += fast_tanh(ax[k0 + 1] * inv);
    }

    // Epilogue h-compute: lane owns dims D0=8sl+2sub, D0+1 -> fp32 residual,
    // tanh, pack to bf16 pair, swizzled LDS store (2-way banks: free).
    float2 f = ((const float2*)feat)[(long long)n * 64 + (4 * sl + sub)];
    float hx = fast_tanh(f.x + 0.5f * s0);
    float hy = fast_tanh(f.y + 0.5f * s1);
    unsigned int hp = (unsigned int)f2bf(hx) | ((unsigned int)f2bf(hy) << 16);
    int wb = wave * 256 + ((16 * sl + 4 * sub) ^ (wave << 4));
    ((unsigned int*)hsb)[wb >> 2] = hp;

    // Waves 0..3: prefetch B-frags + bias from global BEFORE the barrier so
    // the ~300cy latency hides under the sync.
    uint4 b0 = {0,0,0,0}, b1 = {0,0,0,0}, b2 = {0,0,0,0}, b3 = {0,0,0,0};
    float bias = 0.0f;
    int sg = lane >> 4;
    if (wave < 4) {
        int nrow = wave * 16 + (lane & 15);          // output col 0..63
        const uint4* wt4 = (const uint4*)wtbf;       // Wt[n][k] bf16, 16 uint4/row
        b0 = wt4[nrow * 16 +  0 + sg];
        b1 = wt4[nrow * 16 +  4 + sg];
        b2 = wt4[nrow * 16 +  8 + sg];
        b3 = wt4[nrow * 16 + 12 + sg];
        bias = bg[nrow];
    }
    __syncthreads();

    if (wave < 4) {
        // A-frag: lane l -> h row (l&15), k = ks*32 + sg*8 .. +7 (16B, swizzled)
        int row = lane & 15;
        int rbase = row * 256;
        int rx = (row & 7) << 4;
        const uint4* h4 = (const uint4*)hsb;
        uint4 a0 = h4[(rbase + (( 0 + sg * 16) ^ rx)) >> 4];
        uint4 a1 = h4[(rbase + (( 64 + sg * 16) ^ rx)) >> 4];
        uint4 a2 = h4[(rbase + ((128 + sg * 16) ^ rx)) >> 4];
        uint4 a3 = h4[(rbase + ((192 + sg * 16) ^ rx)) >> 4];

        f32x4 c = {bias, bias, bias, bias};          // bias via C-init
        c = __builtin_amdgcn_mfma_f32_16x16x32_bf16(as_s8(a0), as_s8(b0), c, 0, 0, 0);
        c = __builtin_amdgcn_mfma_f32_16x16x32_bf16(as_s8(a1), as_s8(b1), c, 0, 0, 0);
        c = __builtin_amdgcn_mfma_f32_16x16x32_bf16(as_s8(a2), as_s8(b2), c, 0, 0, 0);
        c = __builtin_amdgcn_mfma_f32_16x16x32_bf16(as_s8(a3), as_s8(b3), c, 0, 0, 0);

        // C/D layout (m89-verified): col = lane&15, row = sg*4 + i.
        // Rows 8..15 are the zero padding -> not stored.
        #pragma unroll
        for (int i = 0; i < 4; i++) {
            int orow = sg * 4 + i;
            if (orow < 8)
                out[(long long)(blockIdx.x * 8 + orow) * 64 + wave * 16 + (lane & 15)] = c[i];
        }
    }
}

extern "C" void kernel_launch(void* const* d_in, const int* in_sizes, int n_in,
                              void* d_out, int out_size, void* d_ws, size_t ws_size,
                              hipStream_t stream) {
    const float* feat = (const float*)d_in[0];
    const float* W    = (const float*)d_in[1];
    const float* b    = (const float*)d_in[2];
    const int* edge_index = (const int*)d_in[3];
    float* out = (float*)d_out;

    size_t featbf_bytes  = (size_t)N_NODES * D_IN * sizeof(unsigned short);            // 12.8 MB
    size_t bucket1_bytes = (size_t)N_ETYPES * N_NODES * CAP1 * sizeof(unsigned short); //  4.8 MB
    size_t spill_bytes   = (size_t)N_ETYPES * N_NODES * CAP2 * sizeof(unsigned short); //  9.0 MB
    size_t cnt_bytes     = (size_t)N_ETYPES * N_NODES * sizeof(int);                   //  0.6 MB
    size_t wtbf_bytes    = (size_t)D_IN * D_OUT * sizeof(unsigned short);              // 16 KB
    if (ws_size < featbf_bytes + bucket1_bytes + spill_bytes + cnt_bytes + wtbf_bytes)
        return;  // sentinel: out stays 0 (absmax would read 1.898)

    unsigned short* featbf  = (unsigned short*)d_ws;
    unsigned short* bucket1 = (unsigned short*)((char*)d_ws + featbf_bytes);
    unsigned short* spill   = (unsigned short*)((char*)d_ws + featbf_bytes + bucket1_bytes);
    int* cnt = (int*)((char*)d_ws + featbf_bytes + bucket1_bytes + spill_bytes);
    unsigned short* wtbf = (unsigned short*)((char*)d_ws + featbf_bytes + bucket1_bytes
                                             + spill_bytes + cnt_bytes);   // 16B-aligned (27,200,000)

    hipMemsetAsync(cnt, 0, cnt_bytes, stream);

    convert_kernel<<<NB_FEAT + NB_W, 256, 0, stream>>>(feat, featbf, W, wtbf);

    fill_kernel<<<N_CHUNKS * 8, 256, 0, stream>>>(edge_index, bucket1, spill, cnt);

    gather_linear_kernel<<<N_NODES / 8, 512, 0, stream>>>(
        feat, featbf, wtbf, b, bucket1, spill, cnt, out);
}

// Round 3
// 205.641 us; speedup vs baseline: 1.3039x; 1.0549x over previous
//
#include <hip/hip_runtime.h>
#include <hip/hip_bf16.h>

#define N_NODES 50000
#define D_IN 128
#define D_OUT 64
#define N_ETYPES 3
#define E_PER_ETYPE 500000
#define N_EDGES (N_ETYPES * E_PER_ETYPE)
#define CAP1 16   // primary bucket: 32B (ushort) per cell
#define CAP2 30   // spill (deg>16: ~2.6% of cells; P(deg>46)~1e-18)
#define DMAX (CAP1 + CAP2)                      // 46
#define ZROW N_NODES                             // zero feature row (padding target)
#define NB_FEAT ((N_NODES * D_IN / 4) / 256)    // 6250
#define NB_W ((D_IN * D_OUT) / 256)             // 32
#define NB_ZCNT 147                              // 147*256 int4 >= 37500
#define CHUNK_EDGES 2048                         // 256 thr x 8 edges
#define N_CHUNKS ((N_EDGES + CHUNK_EDGES - 1) / CHUNK_EDGES)   // 733

typedef __attribute__((ext_vector_type(8))) short short8;
typedef __attribute__((ext_vector_type(4))) float f32x4;

static __device__ __forceinline__ unsigned short f2bf(float f) {
    unsigned int x = __float_as_uint(f);
    unsigned int lsb = (x >> 16) & 1u;
    x += 0x7fffu + lsb;          // round-to-nearest-even
    return (unsigned short)(x >> 16);
}

// Branch-free tanh: ~6 VALU vs ~35 for libm tanhf. |err| ~ 1e-6, budget 0.038.
static __device__ __forceinline__ float fast_tanh(float x) {
    float e = __expf(2.0f * x);
    return 1.0f - 2.0f * __builtin_amdgcn_rcpf(e + 1.0f);
}

static __device__ __forceinline__ short8 as_s8(uint4 u) {
    union { uint4 u; short8 s; } cv; cv.u = u; return cv.s;
}

static __device__ __forceinline__ void accum8(float* ax, uint4 p) {
    ax[0] += __uint_as_float(p.x << 16);
    ax[1] += __uint_as_float(p.x & 0xffff0000u);
    ax[2] += __uint_as_float(p.y << 16);
    ax[3] += __uint_as_float(p.y & 0xffff0000u);
    ax[4] += __uint_as_float(p.z << 16);
    ax[5] += __uint_as_float(p.z & 0xffff0000u);
    ax[6] += __uint_as_float(p.w << 16);
    ax[7] += __uint_as_float(p.w & 0xffff0000u);
}

// Reduce-scatter across the 4 subgroups (lanes l, l^16, l^32, l^48 hold
// partials of the same 8 dims). Hierarchical ownership: after xor16 the
// (sub&1)=0 lanes carry dims 0-3 and (sub&1)=1 lanes dims 4-7 (each side
// keeps its half and SENDS the half the partner keeps); after xor32 each
// lane holds its 2 owned dims k0, k0+1 with k0 = ((sub&1)<<2)|(sub&2).
// 24 VALU + 6 bpermutes vs 32 VALU + 16 bpermutes for the full butterfly.
static __device__ __forceinline__ float2 rs_reduce(const float* ax, int sub) {
    bool hi = (sub & 1);
    float k0_ = hi ? ax[4] : ax[0], s0_ = hi ? ax[0] : ax[4];
    float k1_ = hi ? ax[5] : ax[1], s1_ = hi ? ax[1] : ax[5];
    float k2_ = hi ? ax[6] : ax[2], s2_ = hi ? ax[2] : ax[6];
    float k3_ = hi ? ax[7] : ax[3], s3_ = hi ? ax[3] : ax[7];
    float h0 = k0_ + __shfl_xor(s0_, 16);
    float h1 = k1_ + __shfl_xor(s1_, 16);
    float h2 = k2_ + __shfl_xor(s2_, 16);
    float h3 = k3_ + __shfl_xor(s3_, 16);
    bool hi2 = (sub & 2);
    float ka = hi2 ? h2 : h0, sa = hi2 ? h0 : h2;
    float kb = hi2 ? h3 : h1, sb = hi2 ? h1 : h3;
    float2 v;
    v.x = ka + __shfl_xor(sa, 32);
    v.y = kb + __shfl_xor(sb, 32);
    return v;
}

// feat (fp32) -> featbf (bf16) + Wt build + zero-row zero + cnt zero (the
// former hipMemsetAsync, folded in: -1 dispatch; convert precedes fill on the
// stream so ordering is identical).
__global__ __launch_bounds__(256) void convert_kernel(
    const float* __restrict__ feat,
    unsigned short* __restrict__ featbf,
    const float* __restrict__ W,
    unsigned short* __restrict__ wtbf,
    int* __restrict__ cnt)
{
    int b = blockIdx.x;
    if (b < NB_FEAT) {
        int i = b * 256 + threadIdx.x;
        const float4* f4 = (const float4*)feat;
        float4 v = f4[i];
        ushort4 o;
        o.x = f2bf(v.x); o.y = f2bf(v.y); o.z = f2bf(v.z); o.w = f2bf(v.w);
        ((ushort4*)featbf)[i] = o;
    } else if (b < NB_FEAT + NB_W) {
        int i = (b - NB_FEAT) * 256 + threadIdx.x;   // 0..8191
        int n = i >> 7;        // output col 0..63
        int k = i & 127;       // input dim 0..127
        wtbf[i] = f2bf(W[k * D_OUT + n]);   // Wt[n][k] = B^T operand layout
    } else if (b == NB_FEAT + NB_W) {
        // zero row ZROW of featbf (gather's padding target)
        if (threadIdx.x < 64)
            ((unsigned int*)(featbf + (size_t)N_NODES * D_IN))[threadIdx.x] = 0;
    } else {
        int i = (b - NB_FEAT - NB_W - 1) * 256 + threadIdx.x;  // int4 index
        if (i < (N_ETYPES * N_NODES) / 4) {
            int4 z; z.x = 0; z.y = 0; z.z = 0; z.w = 0;
            ((int4*)cnt)[i] = z;
        }
    }
}

// XCD-sliced one-pass binning. UNCHANGED from R9 (attribution: this round's
// delta belongs to gather). dst-space split into 8 slices of 6250 nodes;
// block (chunk, slice=blockIdx&7) bins only dsts in its slice so each XCD's
// write working set fits its private 4MB L2.
__global__ __launch_bounds__(256) void fill_kernel(
    const int* __restrict__ edge_index,
    unsigned short* __restrict__ bucket1,
    unsigned short* __restrict__ spill,
    int* __restrict__ cnt)
{
    int slice = blockIdx.x & 7;
    int chunk = blockIdx.x >> 3;
    int e0 = chunk * CHUNK_EDGES + threadIdx.x;
    #pragma unroll
    for (int k = 0; k < CHUNK_EDGES / 256; k++) {
        int e = e0 + k * 256;
        if (e < N_EDGES) {
            int t  = e / E_PER_ETYPE;            // const divisor -> magic mul
            int ei = e - t * E_PER_ETYPE;
            const int* base = edge_index + (long long)t * 2 * E_PER_ETYPE;
            int dst = base[E_PER_ETYPE + ei];    // coalesced
            // s = dst/6250 exactly, for dst in [0,50000)
            int s = (int)(((unsigned long long)(unsigned)dst * 687195ull) >> 32);
            if (s == slice) {
                int src = base[ei];
                int cell = t * N_NODES + dst;
                int pos = atomicAdd(cnt + cell, 1);
                if (pos < CAP1)
                    bucket1[cell * CAP1 + pos] = (unsigned short)src;
                else if (pos < CAP1 + CAP2)
                    spill[cell * CAP2 + (pos - CAP1)] = (unsigned short)src;
            }
        }
    }
}

// Fused gather + epilogue + MFMA linear. 512 thr = 8 waves; R10: TWO nodes
// per wave (16 nodes/block, grid 3125):
//  - 4 independent 256B gather streams in flight per j-iter (2x latency
//    hiding -- the kernel was latency-bound: ~22us pure VALU vs 70us wall)
//  - ZROW padding: idx lanes >= deg point at the all-zero feat row, making
//    the inner loop fully unconditional (no clamp, no exec-mask churn)
//  - reduce-scatter (rs_reduce) instead of full butterfly
//  - 16x128 h-tile exactly full: no zero-pad rows, MFMA C rows 0..15 all real
__global__ __launch_bounds__(512) void gather_linear_kernel(
    const float* __restrict__ feat,
    const unsigned short* __restrict__ featbf,
    const unsigned short* __restrict__ wtbf,
    const float* __restrict__ bg,
    const unsigned short* __restrict__ bucket1,
    const unsigned short* __restrict__ spill,
    const int* __restrict__ cnt,
    float* __restrict__ out)
{
    __shared__ unsigned short hsb[16 * 128];   // 4KB bf16 h-tile (full)

    int tid = threadIdx.x;
    int wave = tid >> 6;
    int lane = tid & 63;
    int sub  = lane >> 4;     // subgroup 0..3
    int sl   = lane & 15;     // owns dims [8sl..8sl+7] for gather
    int n0 = blockIdx.x * 16 + wave * 2;   // 3125*16 == 50000 exactly
    int n1 = n0 + 1;

    // Preload deg + up to 46 neighbor indices per etype per node, ZROW-padded.
    int degA[N_ETYPES], degB[N_ETYPES], idxA[N_ETYPES], idxB[N_ETYPES];
    #pragma unroll
    for (int t = 0; t < N_ETYPES; t++) {
        int cell = t * N_NODES + n0;                  // n0 even -> int2 aligned
        int2 dg = *(const int2*)(cnt + cell);
        int la = 0, lb = 0;
        if (lane < CAP1) {
            la = bucket1[cell * CAP1 + lane];
            lb = bucket1[(cell + 1) * CAP1 + lane];
        } else if (lane < DMAX) {
            if (dg.x > CAP1) la = spill[cell * CAP2 + (lane - CAP1)];
            if (dg.y > CAP1) lb = spill[(cell + 1) * CAP2 + (lane - CAP1)];
        }
        int ca = dg.x < DMAX ? dg.x : DMAX;
        int cb = dg.y < DMAX ? dg.y : DMAX;
        idxA[t] = (lane < ca) ? la : ZROW;
        idxB[t] = (lane < cb) ? lb : ZROW;
        degA[t] = dg.x; degB[t] = dg.y;
    }

    // Hierarchical dim ownership (must match rs_reduce): k0 in {0,4,2,6}.
    int k0 = ((sub & 1) << 2) | (sub & 2);
    int p2 = 4 * sl + (k0 >> 1);          // float2 index of owned dim pair
    // Residual loads hoisted: independent ~900cy loads overlap the gather.
    float2 fA = ((const float2*)feat)[n0 * 64 + p2];
    float2 fB = ((const float2*)feat)[n1 * 64 + p2];

    const uint4* fb4 = (const uint4*)featbf;   // row = 16 uint4 (256B)
    float s0A = 0.0f, s1A = 0.0f, s0B = 0.0f, s1B = 0.0f;

    #pragma unroll
    for (int t = 0; t < N_ETYPES; t++) {
        int da = degA[t] < DMAX ? degA[t] : DMAX;
        int db = degB[t] < DMAX ? degB[t] : DMAX;
        int dm = da > db ? da : db;
        float axA[8], axB[8];
        #pragma unroll
        for (int k = 0; k < 8; k++) { axA[k] = 0.0f; axB[k] = 0.0f; }
        for (int j = 0; j < dm; j += 8) {
            int r0 = j + sub;                    // rows beyond deg -> ZROW
            int r1 = j + 4 + sub;
            int sa0 = __shfl(idxA[t], r0);
            int sa1 = __shfl(idxA[t], r1);
            int sb0 = __shfl(idxB[t], r0);
            int sb1 = __shfl(idxB[t], r1);
            uint4 pa0 = fb4[sa0 * 16 + sl];      // 4 independent 256B gathers
            uint4 pa1 = fb4[sa1 * 16 + sl];
            uint4 pb0 = fb4[sb0 * 16 + sl];
            uint4 pb1 = fb4[sb1 * 16 + sl];
            accum8(axA, pa0); accum8(axA, pa1);  // unconditional: ZROW adds 0
            accum8(axB, pb0); accum8(axB, pb1);
        }
        float2 vA = rs_reduce(axA, sub);
        float2 vB = rs_reduce(axB, sub);
        float invA = __builtin_amdgcn_rcpf((float)(degA[t] > 0 ? degA[t] : 1));
        float invB = __builtin_amdgcn_rcpf((float)(degB[t] > 0 ? degB[t] : 1));
        s0A += fast_tanh(vA.x * invA);
        s1A += fast_tanh(vA.y * invA);
        s0B += fast_tanh(vB.x * invB);
        s1B += fast_tanh(vB.y * invB);
    }

    // Epilogue h-compute: lane owns dims D0=8sl+k0, D0+1 -> residual, tanh,
    // pack bf16 pair, XOR-swizzled LDS store (byte ^= (row&7)<<4; 2-way: free).
    float hxA = fast_tanh(fA.x + 0.5f * s0A);
    float hyA = fast_tanh(fA.y + 0.5f * s1A);
    float hxB = fast_tanh(fB.x + 0.5f * s0B);
    float hyB = fast_tanh(fB.y + 0.5f * s1B);
    unsigned int hpA = (unsigned int)f2bf(hxA) | ((unsigned int)f2bf(hyA) << 16);
    unsigned int hpB = (unsigned int)f2bf(hxB) | ((unsigned int)f2bf(hyB) << 16);
    int colb = 16 * sl + 2 * k0;
    int rA = wave * 2, rB = rA + 1;
    ((unsigned int*)hsb)[(rA * 256 + (colb ^ ((rA & 7) << 4))) >> 2] = hpA;
    ((unsigned int*)hsb)[(rB * 256 + (colb ^ ((rB & 7) << 4))) >> 2] = hpB;

    // Waves 0..3: prefetch B-frags + bias from global BEFORE the barrier.
    uint4 b0 = {0,0,0,0}, b1 = {0,0,0,0}, b2 = {0,0,0,0}, b3 = {0,0,0,0};
    float bias = 0.0f;
    if (wave < 4) {
        int nrow = wave * 16 + sl;                   // output col 0..63
        const uint4* wt4 = (const uint4*)wtbf;       // Wt[n][k] bf16, 16 uint4/row
        b0 = wt4[nrow * 16 +  0 + sub];
        b1 = wt4[nrow * 16 +  4 + sub];
        b2 = wt4[nrow * 16 +  8 + sub];
        b3 = wt4[nrow * 16 + 12 + sub];
        bias = bg[nrow];
    }
    __syncthreads();

    if (wave < 4) {
        // A-frag: lane l -> h row (l&15), k = ks*32 + sub*8 .. +7 (swizzled)
        int row = sl;
        int rbase = row * 256;
        int rx = (row & 7) << 4;
        const uint4* h4 = (const uint4*)hsb;
        uint4 a0 = h4[(rbase + (( 0 + sub * 16) ^ rx)) >> 4];
        uint4 a1 = h4[(rbase + (( 64 + sub * 16) ^ rx)) >> 4];
        uint4 a2 = h4[(rbase + ((128 + sub * 16) ^ rx)) >> 4];
        uint4 a3 = h4[(rbase + ((192 + sub * 16) ^ rx)) >> 4];

        f32x4 c = {bias, bias, bias, bias};          // bias via C-init
        c = __builtin_amdgcn_mfma_f32_16x16x32_bf16(as_s8(a0), as_s8(b0), c, 0, 0, 0);
        c = __builtin_amdgcn_mfma_f32_16x16x32_bf16(as_s8(a1), as_s8(b1), c, 0, 0, 0);
        c = __builtin_amdgcn_mfma_f32_16x16x32_bf16(as_s8(a2), as_s8(b2), c, 0, 0, 0);
        c = __builtin_amdgcn_mfma_f32_16x16x32_bf16(as_s8(a3), as_s8(b3), c, 0, 0, 0);

        // C/D layout (m89-verified): col = lane&15, row = sub*4 + i.
        // All 16 rows are real nodes now.
        #pragma unroll
        for (int i = 0; i < 4; i++) {
            int orow = sub * 4 + i;
            out[(blockIdx.x * 16 + orow) * 64 + wave * 16 + sl] = c[i];
        }
    }
}

extern "C" void kernel_launch(void* const* d_in, const int* in_sizes, int n_in,
                              void* d_out, int out_size, void* d_ws, size_t ws_size,
                              hipStream_t stream) {
    const float* feat = (const float*)d_in[0];
    const float* W    = (const float*)d_in[1];
    const float* b    = (const float*)d_in[2];
    const int* edge_index = (const int*)d_in[3];
    float* out = (float*)d_out;

    size_t featbf_bytes  = (size_t)(N_NODES + 1) * D_IN * sizeof(unsigned short);      // 12.8 MB (+zero row)
    size_t bucket1_bytes = (size_t)N_ETYPES * N_NODES * CAP1 * sizeof(unsigned short); //  4.8 MB
    size_t spill_bytes   = (size_t)N_ETYPES * N_NODES * CAP2 * sizeof(unsigned short); //  9.0 MB
    size_t cnt_bytes     = (size_t)N_ETYPES * N_NODES * sizeof(int);                   //  0.6 MB
    size_t wtbf_bytes    = (size_t)D_IN * D_OUT * sizeof(unsigned short);              // 16 KB
    if (ws_size < featbf_bytes + bucket1_bytes + spill_bytes + cnt_bytes + wtbf_bytes)
        return;  // sentinel: out stays 0 (absmax would read 1.898)

    unsigned short* featbf  = (unsigned short*)d_ws;
    unsigned short* bucket1 = (unsigned short*)((char*)d_ws + featbf_bytes);
    unsigned short* spill   = (unsigned short*)((char*)d_ws + featbf_bytes + bucket1_bytes);
    int* cnt = (int*)((char*)d_ws + featbf_bytes + bucket1_bytes + spill_bytes);
    unsigned short* wtbf = (unsigned short*)((char*)d_ws + featbf_bytes + bucket1_bytes
                                             + spill_bytes + cnt_bytes);   // 16B-aligned

    // cnt zeroing folded into convert_kernel (same stream order as the old
    // memset: convert precedes fill).
    convert_kernel<<<NB_FEAT + NB_W + 1 + NB_ZCNT, 256, 0, stream>>>(
        feat, featbf, W, wtbf, cnt);

    fill_kernel<<<N_CHUNKS * 8, 256, 0, stream>>>(edge_index, bucket1, spill, cnt);

    gather_linear_kernel<<<N_NODES / 16, 512, 0, stream>>>(
        feat, featbf, wtbf, b, bucket1, spill, cnt, out);
}